// Round 7
// baseline (102.846 us; speedup 1.0000x reference)
//
#include <hip/hip_runtime.h>

#define BB 8
#define TT_DIM 128
#define SS 512
#define DD 512
#define TANH_SCALE 2.885390081777927f   // 2*log2(e)
#define LOG2E 1.4426950408889634f

typedef unsigned short u16;
typedef short short8 __attribute__((ext_vector_type(8)));
typedef float f32x4 __attribute__((ext_vector_type(4)));

__device__ __forceinline__ u16 f2bf(float f) {
  union { float f; unsigned u; } v; v.f = f;
  return (u16)((v.u + 0x7FFFu + ((v.u >> 16) & 1u)) >> 16);
}
__device__ __forceinline__ short8 cvt8(f32x4 a, f32x4 b) {
  short8 o;
  o[0] = (short)f2bf(a[0]); o[1] = (short)f2bf(a[1]);
  o[2] = (short)f2bf(a[2]); o[3] = (short)f2bf(a[3]);
  o[4] = (short)f2bf(b[0]); o[5] = (short)f2bf(b[1]);
  o[6] = (short)f2bf(b[2]); o[7] = (short)f2bf(b[3]);
  return o;
}

// ---------------------------------------------------------------------------
// 64x64 MFMA GEMM body (fp32 in, fp32 out), K=512, strides 512.
// epi=1: exp(2x). trout: write PACKED transpose Ftp[b][d>>3][s][d&7]
// (8 consecutive d contiguous per s -> logits reads 2x dwordx4 per 8 d).
// ---------------------------------------------------------------------------
__device__ __forceinline__ void gemm64_body(
    const float* __restrict__ A, const float* __restrict__ B,
    const float* __restrict__ bias, float* __restrict__ Y,
    int m0, int n0, int epi, bool trout) {
  __shared__ u16 As[64][40];
  __shared__ u16 Bs[64][40];
  int t = threadIdx.x;
  int lane = t & 63, wid = t >> 6, wm = wid >> 1, wn = wid & 1;
  int ar = t >> 2, ac = (t & 3) * 8;
  int bn = t & 63, bk0 = (t >> 6) * 8;
  int fr = lane & 15, fh = (lane >> 4) * 8;

  const f32x4 fzero = {0.f, 0.f, 0.f, 0.f};
  f32x4 acc[2][2];
#pragma unroll
  for (int i = 0; i < 2; ++i)
#pragma unroll
    for (int j = 0; j < 2; ++j) acc[i][j] = fzero;

  short8 av, bv;
  auto loadA = [&](int k0) {
    const float* p = A + (size_t)(m0 + ar) * 512 + k0 + ac;
    av = cvt8(*(const f32x4*)p, *(const f32x4*)(p + 4));
  };
  auto loadB = [&](int k0) {
    const float* p = B + (size_t)(k0 + bk0) * 512 + n0 + bn;
#pragma unroll
    for (int i = 0; i < 8; ++i) bv[i] = (short)f2bf(p[(size_t)i * 512]);
  };

  loadA(0); loadB(0);
  for (int k0 = 0; k0 < 512; k0 += 32) {
    if (k0) __syncthreads();
    *(short8*)&As[ar][ac] = av;
    *(short8*)&Bs[bn][bk0] = bv;
    __syncthreads();
    short8 a0 = *(const short8*)&As[wm * 32 + fr][fh];
    short8 a1 = *(const short8*)&As[wm * 32 + 16 + fr][fh];
    short8 b0 = *(const short8*)&Bs[wn * 32 + fr][fh];
    short8 b1 = *(const short8*)&Bs[wn * 32 + 16 + fr][fh];
    if (k0 + 32 < 512) { loadA(k0 + 32); loadB(k0 + 32); }
    acc[0][0] = __builtin_amdgcn_mfma_f32_16x16x32_bf16(a0, b0, acc[0][0], 0, 0, 0);
    acc[0][1] = __builtin_amdgcn_mfma_f32_16x16x32_bf16(a0, b1, acc[0][1], 0, 0, 0);
    acc[1][0] = __builtin_amdgcn_mfma_f32_16x16x32_bf16(a1, b0, acc[1][0], 0, 0, 0);
    acc[1][1] = __builtin_amdgcn_mfma_f32_16x16x32_bf16(a1, b1, acc[1][1], 0, 0, 0);
  }

  // C/D layout (m89): col = lane&15, row = (lane>>4)*4 + j
#pragma unroll
  for (int qa = 0; qa < 2; ++qa) {
    int rbase = wm * 32 + qa * 16 + ((lane >> 4) << 2);
#pragma unroll
    for (int qn = 0; qn < 2; ++qn) {
      int col = n0 + wn * 32 + qn * 16 + (lane & 15);
      float bvs = bias[col];
      f32x4 v4;
#pragma unroll
      for (int j = 0; j < 4; ++j) {
        float v = acc[qa][qn][j] + bvs;
        if (epi) v = __builtin_amdgcn_exp2f(v * TANH_SCALE);
        v4[j] = v;
      }
      if (trout) {
        int bb = m0 >> 9;
        int srow = (m0 & 511) + rbase;
        size_t base = ((size_t)bb * 64 + (col >> 3)) * 4096 + (size_t)(col & 7);
#pragma unroll
        for (int j = 0; j < 4; ++j)
          Y[base + (size_t)(srow + j) * 8] = v4[j];
      } else {
#pragma unroll
        for (int j = 0; j < 4; ++j)
          Y[(size_t)(m0 + rbase + j) * 512 + col] = v4[j];
      }
    }
  }
}

// blocks [0,16): E = exp(2*(output@dec_w+dec_b))            [1024,512]
// blocks [16,80): Ftp = exp(2*(context@attn_w+attn_b)) packed transpose
// blocks [80,96): G = output@out_w[512:] + out_b            [1024,512]
__global__ __launch_bounds__(256) void ef_gemm(
    const float* __restrict__ output, const float* __restrict__ dec_w,
    const float* __restrict__ dec_b, const float* __restrict__ context,
    const float* __restrict__ attn_w, const float* __restrict__ attn_b,
    const float* __restrict__ out_w, const float* __restrict__ out_b,
    float* __restrict__ E, float* __restrict__ Ftp, float* __restrict__ G) {
  int bx = blockIdx.x;
  const float *A, *Bm, *bias;
  float* Y;
  int m0, epi;
  bool tr;
  if (bx < 16)      { A = output;  Bm = dec_w;  bias = dec_b;  Y = E;   m0 = bx * 64;        epi = 1; tr = false; }
  else if (bx < 80) { A = context; Bm = attn_w; bias = attn_b; Y = Ftp; m0 = (bx - 16) * 64; epi = 1; tr = true; }
  else              { A = output;  Bm = out_w + 512 * 512; bias = out_b; Y = G; m0 = (bx - 80) * 64; epi = 0; tr = false; }
  gemm64_body(A, Bm, bias, Y, m0, blockIdx.y * 64, epi, tr);
}

// ---------------------------------------------------------------------------
// 32x64 MFMA GEMM body. 4 waves 2x2, wave = 16x32.
// ---------------------------------------------------------------------------
template<bool A_BF, bool OUT_BF>
__device__ __forceinline__ void gemm32_body(
    const void* __restrict__ Av, const float* __restrict__ B,
    const float* __restrict__ Cadd, void* __restrict__ Y,
    int m0, int n0, bool do_tanh) {
  __shared__ u16 As[32][40];
  __shared__ u16 Bs[64][40];
  int t = threadIdx.x;
  int lane = t & 63, wid = t >> 6, wm = wid >> 1, wn = wid & 1;
  int ar = t >> 2, ac = (t & 3) * 8;
  int bn = t & 63, bk0 = (t >> 6) * 8;
  int fr = lane & 15, fh = (lane >> 4) * 8;

  const f32x4 fzero = {0.f, 0.f, 0.f, 0.f};
  f32x4 acc[2] = {fzero, fzero};

  short8 av, bv;
  auto loadA = [&](int k0) {
    if (t < 128) {
      if (A_BF) {
        av = *(const short8*)((const u16*)Av + (size_t)(m0 + ar) * 512 + k0 + ac);
      } else {
        const float* p = (const float*)Av + (size_t)(m0 + ar) * 512 + k0 + ac;
        av = cvt8(*(const f32x4*)p, *(const f32x4*)(p + 4));
      }
    }
  };
  auto loadB = [&](int k0) {
    const float* p = B + (size_t)(k0 + bk0) * 512 + n0 + bn;
#pragma unroll
    for (int i = 0; i < 8; ++i) bv[i] = (short)f2bf(p[(size_t)i * 512]);
  };

  loadA(0); loadB(0);
  for (int k0 = 0; k0 < 512; k0 += 32) {
    if (k0) __syncthreads();
    if (t < 128) *(short8*)&As[ar][ac] = av;
    *(short8*)&Bs[bn][bk0] = bv;
    __syncthreads();
    short8 a0 = *(const short8*)&As[wm * 16 + fr][fh];
    short8 b0 = *(const short8*)&Bs[wn * 32 + fr][fh];
    short8 b1 = *(const short8*)&Bs[wn * 32 + 16 + fr][fh];
    if (k0 + 32 < 512) { loadA(k0 + 32); loadB(k0 + 32); }
    acc[0] = __builtin_amdgcn_mfma_f32_16x16x32_bf16(a0, b0, acc[0], 0, 0, 0);
    acc[1] = __builtin_amdgcn_mfma_f32_16x16x32_bf16(a0, b1, acc[1], 0, 0, 0);
  }

  int row0 = m0 + wm * 16 + ((lane >> 4) << 2);
#pragma unroll
  for (int qn = 0; qn < 2; ++qn) {
    int col = n0 + wn * 32 + qn * 16 + (lane & 15);
#pragma unroll
    for (int j = 0; j < 4; ++j) {
      float v = acc[qn][j];
      if (Cadd) v += Cadd[(size_t)(row0 + j) * 512 + col];
      if (do_tanh) {
        float e = __builtin_amdgcn_exp2f(v * TANH_SCALE);
        v = fmaf(-2.0f, __builtin_amdgcn_rcpf(e + 1.0f), 1.0f);
      }
      size_t off = (size_t)(row0 + j) * 512 + col;
      if (OUT_BF) ((u16*)Y)[off] = f2bf(v);
      else ((float*)Y)[off] = v;
    }
  }
}

// mix = attn @ context (batched) -> bf16.  grid (4, 8, 8)
__global__ __launch_bounds__(256) void mix_gemm(
    const float* __restrict__ attn, const float* __restrict__ context,
    u16* __restrict__ mixo) {
  int b = blockIdx.z;
  gemm32_body<false, true>(attn + (size_t)b * TT_DIM * SS,
                           context + (size_t)b * SS * DD, nullptr,
                           mixo + (size_t)b * TT_DIM * DD,
                           blockIdx.x * 32, blockIdx.y * 64, false);
}

// out = tanh(mixo @ out_w[:512] + G).  grid (32, 8)
__global__ __launch_bounds__(256) void final_gemm(
    const u16* __restrict__ mixo, const float* __restrict__ out_w,
    const float* __restrict__ G, float* __restrict__ out) {
  gemm32_body<true, false>(mixo, out_w, G, out,
                           blockIdx.x * 32, blockIdx.y * 64, true);
}

// ---------------------------------------------------------------------------
// Fused logits+softmax. logit[t,s] = base - 2*sum_d q_d/(E[t,d]*F[s,d]+1).
// grid = B*T (1024 blocks), block = 512 (8 waves, 4 blocks/CU = 100% occ).
// Wave: 1 t-row x 64 s (lane = s), d serial in groups of 8 via packed Ftp:
// 2x dwordx4 per lane per 8 d. E/q wave-uniform -> SGPR loads.
// 4 d's share one rcp: sum q_i/x_i = (nA*dB + nB*dA)/(dA*dB).
// ---------------------------------------------------------------------------
__global__ __launch_bounds__(512) void logits_softmax_kernel(
    const float* __restrict__ E, const float* __restrict__ Ftp,
    const float* __restrict__ qw, const float* __restrict__ qb,
    float* __restrict__ attn) {
  int bt = blockIdx.x;
  int b = bt >> 7;  // T = 128
  int tid = threadIdx.x;
  int lane = tid & 63;
  int sc = __builtin_amdgcn_readfirstlane(tid >> 6);  // 0..7
  int s = sc * 64 + lane;

  float qsum = 0.f;
#pragma unroll
  for (int i = 0; i < 8; ++i) qsum += qw[lane + 64 * i];
#pragma unroll
  for (int off = 32; off > 0; off >>= 1) qsum += __shfl_xor(qsum, off, 64);
  float base = qsum + qb[0];

  const float* Fp = Ftp + (size_t)b * 262144 + (size_t)s * 8;  // [g][s][8]
  const float* Et = E + (size_t)bt * 512;

  float accA = 0.f, accB = 0.f;

  auto quad = [&](const f32x4& e, const f32x4& fc, const f32x4& q4, float& acc) {
    float x0 = fmaf(e[0], fc[0], 1.f), x1 = fmaf(e[1], fc[1], 1.f);
    float x2 = fmaf(e[2], fc[2], 1.f), x3 = fmaf(e[3], fc[3], 1.f);
    float dA = x0 * x1, dB = x2 * x3;
    float nA = fmaf(q4[0], x1, q4[1] * x0);
    float nB = fmaf(q4[2], x3, q4[3] * x2);
    float N = fmaf(nA, dB, nB * dA);
    acc = fmaf(N, __builtin_amdgcn_rcpf(dA * dB), acc);
  };

#pragma unroll 4
  for (int g = 0; g < 64; ++g) {
    f32x4 f0 = *(const f32x4*)(Fp + (size_t)g * 4096);
    f32x4 f1 = *(const f32x4*)(Fp + (size_t)g * 4096 + 4);
    f32x4 e0 = *(const f32x4*)(Et + g * 8);
    f32x4 e1 = *(const f32x4*)(Et + g * 8 + 4);
    f32x4 q0 = *(const f32x4*)(qw + g * 8);
    f32x4 q1 = *(const f32x4*)(qw + g * 8 + 4);
    quad(e0, f0, q0, accA);
    quad(e1, f1, q1, accB);
  }

  float l = fmaf(-2.f, accA + accB, base);

  __shared__ float rmax[8], rsum[8];
  float m = l;
#pragma unroll
  for (int off = 32; off > 0; off >>= 1) m = fmaxf(m, __shfl_xor(m, off, 64));
  if (lane == 0) rmax[sc] = m;
  __syncthreads();
  float M = rmax[0];
#pragma unroll
  for (int i = 1; i < 8; ++i) M = fmaxf(M, rmax[i]);
  float ex = __builtin_amdgcn_exp2f((l - M) * LOG2E);
  float sv = ex;
#pragma unroll
  for (int off = 32; off > 0; off >>= 1) sv += __shfl_xor(sv, off, 64);
  if (lane == 0) rsum[sc] = sv;
  __syncthreads();
  float S = 0.f;
#pragma unroll
  for (int i = 0; i < 8; ++i) S += rsum[i];
  attn[(size_t)bt * 512 + s] = ex * __builtin_amdgcn_rcpf(S);
}

extern "C" void kernel_launch(void* const* d_in, const int* in_sizes, int n_in,
                              void* d_out, int out_size, void* d_ws, size_t ws_size,
                              hipStream_t stream) {
  const float* output  = (const float*)d_in[0];  // [B,T,D]
  const float* context = (const float*)d_in[1];  // [B,S,C]
  const float* dec_w   = (const float*)d_in[2];  // [D,D]
  const float* dec_b   = (const float*)d_in[3];
  const float* attn_w  = (const float*)d_in[4];  // [C,D]
  const float* attn_b  = (const float*)d_in[5];
  const float* qw      = (const float*)d_in[6];  // [D,1]
  const float* qb      = (const float*)d_in[7];  // [1]
  const float* out_w   = (const float*)d_in[8];  // [1024,512]
  const float* out_b   = (const float*)d_in[9];

  float* out_p  = (float*)d_out;                     // [B,T,D]
  float* attn_p = out_p + (size_t)BB * TT_DIM * DD;  // [B,T,S]

  char* p = (char*)d_ws;
  float* E   = (float*)p; p += (size_t)BB * TT_DIM * DD * 4;  // 2MB
  float* Ftp = (float*)p; p += (size_t)BB * SS * DD * 4;      // 8MB packed^T
  float* G   = (float*)p; p += (size_t)BB * TT_DIM * DD * 4;  // 2MB
  u16* mixo  = (u16*)p;   p += (size_t)BB * TT_DIM * DD * 2;  // 1MB

  ef_gemm<<<dim3(96, 8), 256, 0, stream>>>(output, dec_w, dec_b, context,
                                           attn_w, attn_b, out_w, out_b,
                                           E, Ftp, G);
  logits_softmax_kernel<<<dim3(BB * TT_DIM), 512, 0, stream>>>(
      E, Ftp, qw, qb, attn_p);
  mix_gemm<<<dim3(4, 8, 8), 256, 0, stream>>>(attn_p, context, mixo);
  final_gemm<<<dim3(32, 8), 256, 0, stream>>>(mixo, out_w, G, out_p);
}

// Round 9
// 69.734 us; speedup vs baseline: 1.4748x; 1.4748x over previous
//
#include <hip/hip_runtime.h>

#define BB 8
#define TT_DIM 128
#define SS 512
#define DD 512
#define TANH_SCALE 2.885390081777927f   // 2*log2(e)
#define LOG2E 1.4426950408889634f

typedef unsigned short u16;
typedef short short8 __attribute__((ext_vector_type(8)));
typedef short short4v __attribute__((ext_vector_type(4)));
typedef float f32x4 __attribute__((ext_vector_type(4)));

__device__ __forceinline__ u16 f2bf(float f) {
  union { float f; unsigned u; } v; v.f = f;
  return (u16)((v.u + 0x7FFFu + ((v.u >> 16) & 1u)) >> 16);
}
__device__ __forceinline__ short8 cvt8(f32x4 a, f32x4 b) {
  short8 o;
  o[0] = (short)f2bf(a[0]); o[1] = (short)f2bf(a[1]);
  o[2] = (short)f2bf(a[2]); o[3] = (short)f2bf(a[3]);
  o[4] = (short)f2bf(b[0]); o[5] = (short)f2bf(b[1]);
  o[6] = (short)f2bf(b[2]); o[7] = (short)f2bf(b[3]);
  return o;
}

// ---------------------------------------------------------------------------
// 64x64 MFMA GEMM body (fp32 A/B in), K=512, strides 512.
// epi=1: exp(2x).  omode: 0 = plain fp32 Y[m,:]
//                          1 = packed transpose fp32  Y[b][d>>3][s][d&7] (Ftp)
//                          2 = transpose bf16         Y[b][col][srow]    (Ht)
// ---------------------------------------------------------------------------
__device__ __forceinline__ void gemm64_body(
    const float* __restrict__ A, const float* __restrict__ B,
    const float* __restrict__ bias, void* __restrict__ Y,
    int m0, int n0, int epi, int omode) {
  __shared__ u16 As[64][40];
  __shared__ u16 Bs[64][40];
  int t = threadIdx.x;
  int lane = t & 63, wid = t >> 6, wm = wid >> 1, wn = wid & 1;
  int ar = t >> 2, ac = (t & 3) * 8;
  int bn = t & 63, bk0 = (t >> 6) * 8;
  int fr = lane & 15, fh = (lane >> 4) * 8;

  const f32x4 fzero = {0.f, 0.f, 0.f, 0.f};
  f32x4 acc[2][2];
#pragma unroll
  for (int i = 0; i < 2; ++i)
#pragma unroll
    for (int j = 0; j < 2; ++j) acc[i][j] = fzero;

  short8 av, bv;
  auto loadA = [&](int k0) {
    const float* p = A + (size_t)(m0 + ar) * 512 + k0 + ac;
    av = cvt8(*(const f32x4*)p, *(const f32x4*)(p + 4));
  };
  auto loadB = [&](int k0) {
    const float* p = B + (size_t)(k0 + bk0) * 512 + n0 + bn;
#pragma unroll
    for (int i = 0; i < 8; ++i) bv[i] = (short)f2bf(p[(size_t)i * 512]);
  };

  loadA(0); loadB(0);
  for (int k0 = 0; k0 < 512; k0 += 32) {
    if (k0) __syncthreads();
    *(short8*)&As[ar][ac] = av;
    *(short8*)&Bs[bn][bk0] = bv;
    __syncthreads();
    short8 a0 = *(const short8*)&As[wm * 32 + fr][fh];
    short8 a1 = *(const short8*)&As[wm * 32 + 16 + fr][fh];
    short8 b0 = *(const short8*)&Bs[wn * 32 + fr][fh];
    short8 b1 = *(const short8*)&Bs[wn * 32 + 16 + fr][fh];
    if (k0 + 32 < 512) { loadA(k0 + 32); loadB(k0 + 32); }
    acc[0][0] = __builtin_amdgcn_mfma_f32_16x16x32_bf16(a0, b0, acc[0][0], 0, 0, 0);
    acc[0][1] = __builtin_amdgcn_mfma_f32_16x16x32_bf16(a0, b1, acc[0][1], 0, 0, 0);
    acc[1][0] = __builtin_amdgcn_mfma_f32_16x16x32_bf16(a1, b0, acc[1][0], 0, 0, 0);
    acc[1][1] = __builtin_amdgcn_mfma_f32_16x16x32_bf16(a1, b1, acc[1][1], 0, 0, 0);
  }

  // C/D layout (m89): col = lane&15, row = (lane>>4)*4 + j
#pragma unroll
  for (int qa = 0; qa < 2; ++qa) {
    int rbase = wm * 32 + qa * 16 + ((lane >> 4) << 2);
#pragma unroll
    for (int qn = 0; qn < 2; ++qn) {
      int col = n0 + wn * 32 + qn * 16 + (lane & 15);
      float bvs = bias ? bias[col] : 0.0f;
      f32x4 v4;
#pragma unroll
      for (int j = 0; j < 4; ++j) {
        float v = acc[qa][qn][j] + bvs;
        if (epi) v = __builtin_amdgcn_exp2f(v * TANH_SCALE);
        v4[j] = v;
      }
      int bb = m0 >> 9;
      int srow = (m0 & 511) + rbase;
      if (omode == 1) {          // packed transpose fp32 (Ftp)
        float* Yf = (float*)Y;
        size_t base = ((size_t)bb * 64 + (col >> 3)) * 4096 + (size_t)(col & 7);
#pragma unroll
        for (int j = 0; j < 4; ++j)
          Yf[base + (size_t)(srow + j) * 8] = v4[j];
      } else if (omode == 2) {   // transpose bf16 (Ht): [b][col][srow]
        u16* Yh = (u16*)Y;
        short4v o;
#pragma unroll
        for (int j = 0; j < 4; ++j) o[j] = (short)f2bf(v4[j]);
        *(short4v*)&Yh[((size_t)bb * 512 + col) * 512 + srow] = o;
      } else {                   // plain fp32
        float* Yf = (float*)Y;
#pragma unroll
        for (int j = 0; j < 4; ++j)
          Yf[(size_t)(m0 + rbase + j) * 512 + col] = v4[j];
      }
    }
  }
}

// blocks [0,16):    E  = exp(2*(output@dec_w+dec_b))          [1024,512]
// blocks [16,80):   Ftp= exp(2*(context@attn_w+attn_b)) packed^T
// blocks [80,96):   G  = output@out_w[512:] + out_b           [1024,512]
// blocks [96,160):  Ht = (context@out_w[:512])^T bf16         [8][512d][512s]
__global__ __launch_bounds__(256) void ef_gemm(
    const float* __restrict__ output, const float* __restrict__ dec_w,
    const float* __restrict__ dec_b, const float* __restrict__ context,
    const float* __restrict__ attn_w, const float* __restrict__ attn_b,
    const float* __restrict__ out_w, const float* __restrict__ out_b,
    float* __restrict__ E, float* __restrict__ Ftp, float* __restrict__ G,
    u16* __restrict__ Ht) {
  int bx = blockIdx.x;
  const float *A, *Bm, *bias;
  void* Y;
  int m0, epi, omode;
  if (bx < 16)       { A = output;  Bm = dec_w;  bias = dec_b;  Y = E;   m0 = bx * 64;        epi = 1; omode = 0; }
  else if (bx < 80)  { A = context; Bm = attn_w; bias = attn_b; Y = Ftp; m0 = (bx - 16) * 64; epi = 1; omode = 1; }
  else if (bx < 96)  { A = output;  Bm = out_w + 512 * 512; bias = out_b; Y = G; m0 = (bx - 80) * 64; epi = 0; omode = 0; }
  else               { A = context; Bm = out_w; bias = nullptr; Y = Ht;  m0 = (bx - 96) * 64; epi = 0; omode = 2; }
  gemm64_body(A, Bm, bias, Y, m0, blockIdx.y * 64, epi, omode);
}

// ---------------------------------------------------------------------------
// final: out = tanh(attn @ Ht^T + G).  32x64 tile, K=512 (s), grid (32, 8).
// A = attn fp32 (cvt in staging). B[k=s][n=dd] = Ht[b][dd][s] -> contiguous
// short8 loads. G added in epilogue.
// ---------------------------------------------------------------------------
__global__ __launch_bounds__(256) void final_gemm(
    const float* __restrict__ attn, const u16* __restrict__ Ht,
    const float* __restrict__ G, float* __restrict__ out) {
  int m0 = blockIdx.x * 32, n0 = blockIdx.y * 64;
  int b = m0 >> 7;   // T = 128
  const u16* Htb = Ht + (size_t)b * 512 * 512;

  __shared__ u16 As[32][40];
  __shared__ u16 Bs[64][40];
  int t = threadIdx.x;
  int lane = t & 63, wid = t >> 6, wm = wid >> 1, wn = wid & 1;
  int ar = t >> 2, ac = (t & 3) * 8;     // t<128 stages A (32 rows)
  int bn = t & 63, bk0 = (t >> 6) * 8;
  int fr = lane & 15, fh = (lane >> 4) * 8;

  const f32x4 fzero = {0.f, 0.f, 0.f, 0.f};
  f32x4 acc[2] = {fzero, fzero};

  short8 av, bv;
  auto loadA = [&](int k0) {
    if (t < 128) {
      const float* p = attn + (size_t)(m0 + ar) * 512 + k0 + ac;
      av = cvt8(*(const f32x4*)p, *(const f32x4*)(p + 4));
    }
  };
  auto loadB = [&](int k0) {
    bv = *(const short8*)(Htb + (size_t)(n0 + bn) * 512 + k0 + bk0);
  };

  loadA(0); loadB(0);
  for (int k0 = 0; k0 < 512; k0 += 32) {
    if (k0) __syncthreads();
    if (t < 128) *(short8*)&As[ar][ac] = av;
    *(short8*)&Bs[bn][bk0] = bv;
    __syncthreads();
    short8 a0 = *(const short8*)&As[wm * 16 + fr][fh];
    short8 b0 = *(const short8*)&Bs[wn * 32 + fr][fh];
    short8 b1 = *(const short8*)&Bs[wn * 32 + 16 + fr][fh];
    if (k0 + 32 < 512) { loadA(k0 + 32); loadB(k0 + 32); }
    acc[0] = __builtin_amdgcn_mfma_f32_16x16x32_bf16(a0, b0, acc[0], 0, 0, 0);
    acc[1] = __builtin_amdgcn_mfma_f32_16x16x32_bf16(a0, b1, acc[1], 0, 0, 0);
  }

  int row0 = m0 + wm * 16 + ((lane >> 4) << 2);
#pragma unroll
  for (int qn = 0; qn < 2; ++qn) {
    int col = n0 + wn * 32 + qn * 16 + (lane & 15);
#pragma unroll
    for (int j = 0; j < 4; ++j) {
      float v = acc[qn][j] + G[(size_t)(row0 + j) * 512 + col];
      float e = __builtin_amdgcn_exp2f(v * TANH_SCALE);
      v = fmaf(-2.0f, __builtin_amdgcn_rcpf(e + 1.0f), 1.0f);
      out[(size_t)(row0 + j) * 512 + col] = v;
    }
  }
}

// ---------------------------------------------------------------------------
// Fused logits+softmax. logit[t,s] = base - 2*sum_d q_d/(E[t,d]*F[s,d]+1).
// grid = B*T/2 = 512 blocks (XCD-swizzled), block = 512 (8 waves).
// Block: 2 t-rows x 512 s; wave sc owns s-chunk, lane = s. d in groups of 8
// (packed Ftp: 2x dwordx4/lane). E/q wave-uniform -> SGPR. 4 acc chains.
// ---------------------------------------------------------------------------
__global__ __launch_bounds__(512) void logits_softmax_kernel(
    const float* __restrict__ E, const float* __restrict__ Ftp,
    const float* __restrict__ qw, const float* __restrict__ qb,
    float* __restrict__ attn) {
  int bid = blockIdx.x;
  int logical = ((bid & 7) << 6) | (bid >> 3);  // XCD gets one batch slab
  int bt0 = logical * 2;
  int b = bt0 >> 7;  // T = 128  (R8 BUG was >>8: wrong F slab for 7/8 blocks)
  int tid = threadIdx.x;
  int lane = tid & 63;
  int sc = __builtin_amdgcn_readfirstlane(tid >> 6);  // 0..7
  int s = sc * 64 + lane;

  float qsum = 0.f;
#pragma unroll
  for (int i = 0; i < 8; ++i) qsum += qw[lane + 64 * i];
#pragma unroll
  for (int off = 32; off > 0; off >>= 1) qsum += __shfl_xor(qsum, off, 64);
  float base = qsum + qb[0];

  const float* Fp = Ftp + (size_t)b * 262144 + (size_t)s * 8;  // [g][s][8]
  const float* Et0 = E + (size_t)bt0 * 512;
  const float* Et1 = Et0 + 512;

  float a0A = 0.f, a0B = 0.f, a1A = 0.f, a1B = 0.f;

  auto quad = [&](const f32x4& e, const f32x4& fc, const f32x4& q4, float& acc) {
    float x0 = fmaf(e[0], fc[0], 1.f), x1 = fmaf(e[1], fc[1], 1.f);
    float x2 = fmaf(e[2], fc[2], 1.f), x3 = fmaf(e[3], fc[3], 1.f);
    float dA = x0 * x1, dB = x2 * x3;
    float nA = fmaf(q4[0], x1, q4[1] * x0);
    float nB = fmaf(q4[2], x3, q4[3] * x2);
    float N = fmaf(nA, dB, nB * dA);
    acc = fmaf(N, __builtin_amdgcn_rcpf(dA * dB), acc);
  };

#pragma unroll 4
  for (int g = 0; g < 64; ++g) {
    f32x4 f0 = *(const f32x4*)(Fp + (size_t)g * 4096);
    f32x4 f1 = *(const f32x4*)(Fp + (size_t)g * 4096 + 4);
    f32x4 q0 = *(const f32x4*)(qw + g * 8);
    f32x4 q1 = *(const f32x4*)(qw + g * 8 + 4);
    f32x4 e00 = *(const f32x4*)(Et0 + g * 8);
    f32x4 e01 = *(const f32x4*)(Et0 + g * 8 + 4);
    f32x4 e10 = *(const f32x4*)(Et1 + g * 8);
    f32x4 e11 = *(const f32x4*)(Et1 + g * 8 + 4);
    quad(e00, f0, q0, a0A);
    quad(e01, f1, q1, a0B);
    quad(e10, f0, q0, a1A);
    quad(e11, f1, q1, a1B);
  }

  float l0 = fmaf(-2.f, a0A + a0B, base);
  float l1 = fmaf(-2.f, a1A + a1B, base);

  __shared__ float rmax[2][8], rsum[2][8];
  float m0 = l0, m1 = l1;
#pragma unroll
  for (int off = 32; off > 0; off >>= 1) {
    m0 = fmaxf(m0, __shfl_xor(m0, off, 64));
    m1 = fmaxf(m1, __shfl_xor(m1, off, 64));
  }
  if (lane == 0) { rmax[0][sc] = m0; rmax[1][sc] = m1; }
  __syncthreads();
  float M0 = rmax[0][0], M1 = rmax[1][0];
#pragma unroll
  for (int i = 1; i < 8; ++i) {
    M0 = fmaxf(M0, rmax[0][i]);
    M1 = fmaxf(M1, rmax[1][i]);
  }
  float ex0 = __builtin_amdgcn_exp2f((l0 - M0) * LOG2E);
  float ex1 = __builtin_amdgcn_exp2f((l1 - M1) * LOG2E);
  float s0v = ex0, s1v = ex1;
#pragma unroll
  for (int off = 32; off > 0; off >>= 1) {
    s0v += __shfl_xor(s0v, off, 64);
    s1v += __shfl_xor(s1v, off, 64);
  }
  if (lane == 0) { rsum[0][sc] = s0v; rsum[1][sc] = s1v; }
  __syncthreads();
  float S0 = 0.f, S1 = 0.f;
#pragma unroll
  for (int i = 0; i < 8; ++i) { S0 += rsum[0][i]; S1 += rsum[1][i]; }
  attn[(size_t)bt0 * 512 + s] = ex0 * __builtin_amdgcn_rcpf(S0);
  attn[(size_t)(bt0 + 1) * 512 + s] = ex1 * __builtin_amdgcn_rcpf(S1);
}

extern "C" void kernel_launch(void* const* d_in, const int* in_sizes, int n_in,
                              void* d_out, int out_size, void* d_ws, size_t ws_size,
                              hipStream_t stream) {
  const float* output  = (const float*)d_in[0];  // [B,T,D]
  const float* context = (const float*)d_in[1];  // [B,S,C]
  const float* dec_w   = (const float*)d_in[2];  // [D,D]
  const float* dec_b   = (const float*)d_in[3];
  const float* attn_w  = (const float*)d_in[4];  // [C,D]
  const float* attn_b  = (const float*)d_in[5];
  const float* qw      = (const float*)d_in[6];  // [D,1]
  const float* qb      = (const float*)d_in[7];  // [1]
  const float* out_w   = (const float*)d_in[8];  // [1024,512]
  const float* out_b   = (const float*)d_in[9];

  float* out_p  = (float*)d_out;                     // [B,T,D]
  float* attn_p = out_p + (size_t)BB * TT_DIM * DD;  // [B,T,S]

  char* p = (char*)d_ws;
  float* E   = (float*)p; p += (size_t)BB * TT_DIM * DD * 4;  // 2MB
  float* Ftp = (float*)p; p += (size_t)BB * SS * DD * 4;      // 8MB packed^T
  float* G   = (float*)p; p += (size_t)BB * TT_DIM * DD * 4;  // 2MB
  u16* Ht    = (u16*)p;   p += (size_t)BB * SS * DD * 2;      // 4MB bf16 ^T

  ef_gemm<<<dim3(160, 8), 256, 0, stream>>>(output, dec_w, dec_b, context,
                                            attn_w, attn_b, out_w, out_b,
                                            E, Ftp, G, Ht);
  logits_softmax_kernel<<<dim3(BB * TT_DIM / 2), 512, 0, stream>>>(
      E, Ftp, qw, qb, attn_p);
  final_gemm<<<dim3(32, 8), 256, 0, stream>>>(attn_p, Ht, G, out_p);
}